// Round 2
// baseline (2184.979 us; speedup 1.0000x reference)
//
#include <hip/hip_runtime.h>
#include <cstdint>
#include <cstddef>

// ---------------- problem constants ----------------
#define B_    64
#define N_    197
#define DIM_  768
#define NH_   12
#define HD_   64
#define NP_   196
#define SCALE_ 0.125f
#define EPS_   1.1920929e-07f
#define BN_EPS_ 1e-5f
#define ALPHA_ 0.01f

#define M_TOK   (B_*N_)        // 12608
#define M_PATCH (B_*NP_)       // 12544
#define OUT_MAIN (M_TOK*DIM_)  // 9682944

// scalar workspace layout (float offsets within SC)
#define W_OFF     0      // 3 blend weights
#define HP_OFF    16     // 12*9 head-prob softmax
#define HPROW_OFF 128    // 12 row sums of hp
#define NVB_OFF   144    // 64*9 new_vb [d][k]
#define SVB_OFF   720    // 64 sum_k new_vb
#define STATS_OFF 784    // 128: sum[64], sumsq[64]
#define W1_OFF    1024   // 768*64
#define W3_OFF    50176  // 768*64
#define PART_OFF  99328  // 256*128 partials
#define SC_FLOATS 132096

// ---------------- prep: scalars, hp, new_vb, ki/kt ----------------
__global__ void prep_kernel(const float* __restrict__ uniforms, const float* __restrict__ kth,
                            const float* __restrict__ head_probs, const float* __restrict__ v_b,
                            float* __restrict__ SC, float* __restrict__ out_tail)
{
    int t = threadIdx.x;
    if (t == 0) {
        float ind[3];
        for (int i = 0; i < 3; i++) {
            float s = 1.f/(1.f + expf(-kth[i]));
            float p = fminf(fmaxf(s, EPS_), 1.f - EPS_);
            float u = fminf(fmaxf(uniforms[i], EPS_), 1.f - EPS_);
            float logit = logf(u) - log1pf(-u) + logf(p) - log1pf(-p);
            ind[i] = (logit > 0.f) ? 1.f : 0.f;
        }
        SC[W_OFF+0] = ind[2];
        SC[W_OFF+1] = ind[1]*(1.f-ind[2]);
        SC[W_OFF+2] = ind[0]*(1.f-ind[1])*(1.f-ind[2]);
        float kprod = 1.f;
        for (int i = 0; i < 3; i++) {
            float ktv = 1.f/(1.f + expf(-kth[i]));
            kprod *= (ktv > 0.5f) ? 1.f : 0.f;
            out_tail[i]   = kprod;   // ki (cumprod)
            out_tail[3+i] = ktv;     // kt
        }
    }
    if (t < 9) {
        float mx = -1e30f;
        for (int h = 0; h < 12; h++) mx = fmaxf(mx, head_probs[h*9+t]);
        float e[12]; float s = 0.f;
        for (int h = 0; h < 12; h++) { e[h] = expf((head_probs[h*9+t]-mx)/ALPHA_); s += e[h]; }
        for (int h = 0; h < 12; h++) SC[HP_OFF + h*9 + t] = e[h]/s;
    }
    __syncthreads();
    if (t < 12) {
        float s = 0.f;
        for (int k = 0; k < 9; k++) s += SC[HP_OFF + t*9 + k];
        SC[HPROW_OFF + t] = s;
    }
    if (t < 64) {
        float sv = 0.f;
        for (int k = 0; k < 9; k++) {
            float s = 0.f;
            for (int h = 0; h < 12; h++) s += v_b[h*64+t]*SC[HP_OFF + h*9 + k];
            SC[NVB_OFF + t*9 + k] = s;
            sv += s;
        }
        SC[SVB_OFF + t] = sv;
    }
}

// ---------------- generic GEMM: C[M x Nc] = A[M x K] @ W[Nc x K]^T (+bias) ----------------
#define GT 64
#define GK 16
template<bool BIAS>
__global__ __launch_bounds__(256) void gemm_xwt(
    const float* __restrict__ A, const float* __restrict__ W,
    const float* __restrict__ bias, float* __restrict__ C,
    int M, int Ncols, int K)
{
    __shared__ float As[GK][GT+4];
    __shared__ float Bs[GK][GT+4];
    const int tid = threadIdx.x;
    const int tx = tid & 15, ty = tid >> 4;
    const int m0 = blockIdx.y * GT, n0 = blockIdx.x * GT;
    float acc[4][4] = {};
    for (int k0 = 0; k0 < K; k0 += GK) {
        #pragma unroll
        for (int i = 0; i < 4; i++) {
            int r = ty + i*16;
            As[tx][r] = A[(size_t)(m0 + r)*K + (k0 + tx)];
            Bs[tx][r] = W[(size_t)(n0 + r)*K + (k0 + tx)];
        }
        __syncthreads();
        #pragma unroll
        for (int kk = 0; kk < GK; kk++) {
            const float4 a4 = *(const float4*)&As[kk][ty*4];
            const float4 b4 = *(const float4*)&Bs[kk][tx*4];
            const float a[4] = {a4.x, a4.y, a4.z, a4.w};
            const float b[4] = {b4.x, b4.y, b4.z, b4.w};
            #pragma unroll
            for (int i = 0; i < 4; i++)
                #pragma unroll
                for (int j = 0; j < 4; j++)
                    acc[i][j] += a[i]*b[j];
        }
        __syncthreads();
    }
    #pragma unroll
    for (int i = 0; i < 4; i++) {
        int m = m0 + ty*4 + i;
        #pragma unroll
        for (int j = 0; j < 4; j++) {
            int n = n0 + tx*4 + j;
            float v = acc[i][j];
            if (BIAS) v += bias[n];
            C[(size_t)m*Ncols + n] = v;
        }
    }
}

// ---------------- attention: per (b,h), 16 rows per block; barrier-ordered softmax ----------------
__global__ __launch_bounds__(256) void attn_kernel(
    const float* __restrict__ qk, const float* __restrict__ vw,
    const float* __restrict__ v_b, float* __restrict__ msa)
{
    __shared__ float q_lds[16][64];
    __shared__ float p_lds[16][200];
    __shared__ float red[16][17];
    __shared__ float rstat[16];
    const int bh = blockIdx.x;
    const int b = bh / NH_, h = bh % NH_;
    const int r0 = blockIdx.y * 16;
    const int tid = threadIdx.x;
    for (int i = tid; i < 16*64; i += 256) {
        int r = i >> 6, d = i & 63;
        int n = r0 + r;
        q_lds[r][d] = (n < N_) ? qk[(size_t)(b*N_ + n)*1536 + h*64 + d] : 0.f;
    }
    __syncthreads();
    const int r = tid >> 4, g = tid & 15;
    const int n = r0 + r;
    for (int m = g; m < N_; m += 16) {
        const float* krow = qk + (size_t)(b*N_ + m)*1536 + 768 + h*64;
        float s = 0.f;
        #pragma unroll
        for (int d = 0; d < 64; d += 4) {
            s += q_lds[r][d]*krow[d] + q_lds[r][d+1]*krow[d+1]
               + q_lds[r][d+2]*krow[d+2] + q_lds[r][d+3]*krow[d+3];
        }
        p_lds[r][m] = s * SCALE_;
    }
    __syncthreads();
    // row max via LDS partials
    {
        float mx = -1e30f;
        for (int m = g; m < N_; m += 16) mx = fmaxf(mx, p_lds[r][m]);
        red[r][g] = mx;
    }
    __syncthreads();
    if (g == 0) {
        float v = red[r][0];
        #pragma unroll
        for (int t = 1; t < 16; t++) v = fmaxf(v, red[r][t]);
        rstat[r] = v;
    }
    __syncthreads();
    {
        float mx = rstat[r];
        float sum = 0.f;
        for (int m = g; m < N_; m += 16) { float e = __expf(p_lds[r][m] - mx); p_lds[r][m] = e; sum += e; }
        red[r][g] = sum;
    }
    __syncthreads();
    if (g == 0) {
        float v = 0.f;
        #pragma unroll
        for (int t = 0; t < 16; t++) v += red[r][t];
        rstat[r] = v;
    }
    __syncthreads();
    {
        float inv = 1.f/rstat[r];
        for (int m = g; m < N_; m += 16) p_lds[r][m] *= inv;
    }
    __syncthreads();
    if (n < N_) {
        float acc0=0.f, acc1=0.f, acc2=0.f, acc3=0.f;
        for (int m = 0; m < N_; m++) {
            float p = p_lds[r][m];
            const float* vrow = vw + (size_t)(b*N_ + m)*768 + h*64 + g;
            acc0 += p*vrow[0]; acc1 += p*vrow[16]; acc2 += p*vrow[32]; acc3 += p*vrow[48];
        }
        float* orow = msa + (size_t)(b*N_ + n)*768 + h*64 + g;
        const float* vbp = v_b + h*64 + g;
        orow[0]  = acc0 + vbp[0];
        orow[16] = acc1 + vbp[16];
        orow[32] = acc2 + vbp[32];
        orow[48] = acc3 + vbp[48];
    }
}

// ---------------- new_v: (B,196,9,64) = sum_h v_weight[:,1:,h,d]*hp[h,k] ----------------
__global__ __launch_bounds__(256) void newv_kernel(
    const float* __restrict__ vw, const float* __restrict__ SC, float* __restrict__ newv)
{
    int idx = blockIdx.x*256 + threadIdx.x;
    if (idx >= M_PATCH*64) return;
    int d = idx & 63; int bp = idx >> 6;
    int p = bp % NP_, b = bp / NP_;
    const float* src = vw + (size_t)(b*N_ + 1 + p)*768 + d;
    float vh[12];
    #pragma unroll
    for (int h = 0; h < 12; h++) vh[h] = src[h*64];
    #pragma unroll
    for (int k = 0; k < 9; k++) {
        float s = 0.f;
        #pragma unroll
        for (int h = 0; h < 12; h++) s += vh[h]*SC[HP_OFF + h*9 + k];
        newv[((size_t)bp*9 + k)*64 + d] = s;
    }
}

__global__ __launch_bounds__(256) void c1pre_kernel(
    const float* __restrict__ newv, const float* __restrict__ SC, float* __restrict__ dst)
{
    int i = blockIdx.x*256 + threadIdx.x;
    if (i >= M_PATCH*64) return;
    int d = i & 63; int bp = i >> 6;
    dst[i] = newv[((size_t)bp*9 + 4)*64 + d] + SC[NVB_OFF + d*9 + 4];
}

__global__ __launch_bounds__(256) void c3pre_kernel(
    const float* __restrict__ newv, const float* __restrict__ SC, float* __restrict__ dst)
{
    int i = blockIdx.x*256 + threadIdx.x;
    if (i >= M_PATCH*64) return;
    int d = i & 63; int bij = i >> 6;
    int j = bij % 14; int bi = bij / 14; int irow = bi % 14; int b = bi / 14;
    float acc = SC[SVB_OFF + d];
    #pragma unroll
    for (int p = 0; p < 9; p++) {
        int h1 = p % 3, h2 = p / 3;
        int y = irow + h1 - 1, x = j + h2 - 1;
        if (y >= 0 && y < 14 && x >= 0 && x < 14)
            acc += newv[(((size_t)b*NP_ + y*14 + x)*9 + p)*64 + d];
    }
    dst[i] = acc;
}

// ---------------- BN: deterministic two-stage reduce then apply+relu ----------------
__global__ __launch_bounds__(256) void bnstat_kernel(
    const float* __restrict__ src, int nelem, float* __restrict__ partial)
{
    __shared__ float sd[256], sq[256];
    int tid = threadIdx.x;
    float s = 0.f, q = 0.f;
    int stride = gridDim.x * 256;   // multiple of 64 -> each thread stays on one channel
    for (int i = blockIdx.x*256 + tid; i < nelem; i += stride) {
        float v = src[i]; s += v; q += v*v;
    }
    sd[tid] = s; sq[tid] = q;
    __syncthreads();
    if (tid < 64) {
        float ts = sd[tid]+sd[tid+64]+sd[tid+128]+sd[tid+192];
        float tq = sq[tid]+sq[tid+64]+sq[tid+128]+sq[tid+192];
        partial[blockIdx.x*128 + tid]      = ts;
        partial[blockIdx.x*128 + 64 + tid] = tq;
    }
}

__global__ void bnreduce_kernel(const float* __restrict__ partial, int nblk, float* __restrict__ stats)
{
    int t = threadIdx.x;  // 128
    float s = 0.f;
    for (int i = 0; i < nblk; i++) s += partial[i*128 + t];
    stats[t] = s;
}

__global__ __launch_bounds__(256) void bnapply_kernel(
    float* __restrict__ buf, int nelem, const float* __restrict__ stats,
    const float* __restrict__ g, const float* __restrict__ bb, float invN)
{
    int i = blockIdx.x*256 + threadIdx.x;
    if (i >= nelem) return;
    int d = i & 63;
    float mean = stats[d]*invN;
    float var  = stats[64+d]*invN - mean*mean;
    float sc = rsqrtf(var + BN_EPS_) * g[d];
    float v = (buf[i] - mean)*sc + bb[d];
    buf[i] = fmaxf(v, 0.f);
}

// ---------------- W1/W3 reduction over heads ----------------
__global__ __launch_bounds__(256) void w13_kernel(
    const float* __restrict__ proj_w, const float* __restrict__ SC,
    float* __restrict__ W1, float* __restrict__ W3)
{
    int idx = blockIdx.x*256 + threadIdx.x;
    if (idx >= 768*64) return;
    int d = idx & 63, c = idx >> 6;
    float s1 = 0.f, s3 = 0.f;
    #pragma unroll
    for (int h = 0; h < 12; h++) {
        float pw = proj_w[(size_t)c*768 + h*64 + d];
        s1 += pw * SC[HP_OFF + h*9 + 4];
        s3 += pw * SC[HPROW_OFF + h];
    }
    W1[idx] = s1; W3[idx] = s3;  // [c][d]
}

// ---------------- final blend: write-only to out ----------------
__global__ __launch_bounds__(256) void blend_kernel(
    const float* __restrict__ x, const float* __restrict__ pbuf,
    const float* __restrict__ c1o, const float* __restrict__ c3o,
    const float* __restrict__ SC, float* __restrict__ out)
{
    int i = blockIdx.x*256 + threadIdx.x;
    if (i >= OUT_MAIN) return;
    int cc = i % 768; int bn = i / 768; int n = bn % 197;
    float w0 = SC[0], w1 = SC[1], w2 = SC[2];
    float m = pbuf[i];
    float c1v, c3v;
    if (n == 0) { c1v = x[i]; c3v = x[i]; }
    else {
        size_t q = ((size_t)(bn - (bn/197) - 1))*768 + cc;  // (b*196 + n-1)*768 + cc
        c1v = c1o[q]; c3v = c3o[q];
    }
    out[i] = w0*m + w1*c3v + w2*c1v;
}

// ---------------- launch ----------------
extern "C" void kernel_launch(void* const* d_in, const int* in_sizes, int n_in,
                              void* d_out, int out_size, void* d_ws, size_t ws_size,
                              hipStream_t stream)
{
    const float* x        = (const float*)d_in[0];
    const float* uniforms = (const float*)d_in[1];
    const float* qk_w     = (const float*)d_in[2];
    const float* qk_b     = (const float*)d_in[3];
    const float* v_w      = (const float*)d_in[4];
    const float* v_b      = (const float*)d_in[5];
    const float* proj_w   = (const float*)d_in[6];
    const float* proj_b   = (const float*)d_in[7];
    const float* bn1_g    = (const float*)d_in[8];
    const float* bn1_b    = (const float*)d_in[9];
    const float* bn3_g    = (const float*)d_in[10];
    const float* bn3_b    = (const float*)d_in[11];
    const float* kth      = (const float*)d_in[12];
    const float* head_probs = (const float*)d_in[13];
    float* out = (float*)d_out;

    // ws layout (all same-call write-before-read; aliases rewritten in full first):
    float* ws     = (float*)d_ws;
    float* qkbuf  = ws;                        // [0, 19,365,888)  (B,N,1536)
    float* vw     = qkbuf + 19365888;          // [.., +9,682,944) (B,N,768)
    float* pbuf   = vw + 9682944;              // [.., +9,682,944) proj output
    float* SC     = pbuf + 9682944;            // [.., +132,096)
    // aliases:
    float* newv   = qkbuf;                     // 7,225,344 floats (after attn read qkbuf)
    float* c1out  = qkbuf;                     // 9,633,792 (written after newv last read)
    float* c3out  = qkbuf + 9633792;           // 9,633,792 (disjoint from newv)
    float* c1buf  = vw;                        // 802,816 (after vw last read)
    float* c3buf  = vw + 802816;               // 802,816
    float* msa    = out;                       // out used as early scratch; blend rewrites fully
    float* W1     = SC + W1_OFF;
    float* W3     = SC + W3_OFF;
    float* stats  = SC + STATS_OFF;
    float* part   = SC + PART_OFF;

    prep_kernel<<<1, 256, 0, stream>>>(uniforms, kth, head_probs, v_b, SC, out + OUT_MAIN);

    // qk = x @ qk_w^T + qk_b   (B*N x 1536)
    gemm_xwt<true><<<dim3(24,197), 256, 0, stream>>>(x, qk_w, qk_b, qkbuf, M_TOK, 1536, 768);
    // v_weight = x @ v_w^T     (B*N x 768)
    gemm_xwt<false><<<dim3(12,197), 256, 0, stream>>>(x, v_w, nullptr, vw, M_TOK, 768, 768);
    // attention -> msa (scratch in d_out)
    attn_kernel<<<dim3(768,13), 256, 0, stream>>>(qkbuf, vw, v_b, msa);
    // proj -> pbuf
    gemm_xwt<true><<<dim3(12,197), 256, 0, stream>>>(msa, proj_w, proj_b, pbuf, M_TOK, 768, 768);

    // new_v from v_weight (into qkbuf; attn is done with qkbuf)
    newv_kernel<<<3136, 256, 0, stream>>>(vw, SC, newv);

    // c1 branch
    c1pre_kernel<<<3136, 256, 0, stream>>>(newv, SC, c1buf);
    bnstat_kernel<<<256, 256, 0, stream>>>(c1buf, M_PATCH*64, part);
    bnreduce_kernel<<<1, 128, 0, stream>>>(part, 256, stats);
    bnapply_kernel<<<3136, 256, 0, stream>>>(c1buf, M_PATCH*64, stats, bn1_g, bn1_b, 1.0f/12544.0f);

    // c3 branch
    c3pre_kernel<<<3136, 256, 0, stream>>>(newv, SC, c3buf);
    bnstat_kernel<<<256, 256, 0, stream>>>(c3buf, M_PATCH*64, part);
    bnreduce_kernel<<<1, 128, 0, stream>>>(part, 256, stats);
    bnapply_kernel<<<3136, 256, 0, stream>>>(c3buf, M_PATCH*64, stats, bn3_g, bn3_b, 1.0f/12544.0f);

    // per-branch projection weights
    w13_kernel<<<192, 256, 0, stream>>>(proj_w, SC, W1, W3);

    // c1/c3 output GEMMs (K=64); write after newv's last read (c3pre)
    gemm_xwt<true><<<dim3(12,196), 256, 0, stream>>>(c1buf, W1, proj_b, c1out, M_PATCH, 768, 64);
    gemm_xwt<true><<<dim3(12,196), 256, 0, stream>>>(c3buf, W3, proj_b, c3out, M_PATCH, 768, 64);

    // final blend: single write of out
    blend_kernel<<<37824, 256, 0, stream>>>(x, pbuf, c1out, c3out, SC, out);
}